// Round 1
// baseline (1040.915 us; speedup 1.0000x reference)
//
#include <hip/hip_runtime.h>
#include <hip/hip_bf16.h>
#include <stdint.h>

typedef short s8v __attribute__((ext_vector_type(8)));
typedef float f4v __attribute__((ext_vector_type(4)));

__device__ __forceinline__ void async_copy16(const void* gsrc, void* lds_dst) {
  __builtin_amdgcn_global_load_lds(
      (const __attribute__((address_space(1))) uint32_t*)(uintptr_t)gsrc,
      (__attribute__((address_space(3))) uint32_t*)(uint32_t)(uintptr_t)lds_dst,
      16, 0, 0);
}

// ---------------- W pack: [co][ci][kh][kw] fp32 -> [kh*5+kw][co][ci] bf16 ----------------
__global__ void wpack_kernel(const float* __restrict__ W, __hip_bfloat16* __restrict__ Wr) {
  int i = blockIdx.x * 256 + threadIdx.x;  // < 819200
  int ci = i & 255;
  int rest = i >> 8;
  int co = rest & 127;
  int pos = rest >> 7;  // kh*5+kw
  Wr[i] = __float2bfloat16(W[(co * 256 + ci) * 25 + pos]);
}

// ---------------- Upsample: x NCHW fp32 (8,256,64,64) -> up NHWC bf16 (8,128,128,256) ----------------
// grid: b(8) x cb(4,64ch) x ohb(8,16 rows) x owb(2,64 cols) = 512 blocks
__global__ __launch_bounds__(256, 2) void upsample_kernel(const float* __restrict__ x,
                                                          __hip_bfloat16* __restrict__ up) {
  __shared__ __hip_bfloat16 lx[10 * 48 * 66];  // [ih 10][iw 48][c 64 + 2 pad]
  const int tid = threadIdx.x;
  const int bx = blockIdx.x;
  const int owb = bx & 1;
  const int ohb = (bx >> 1) & 7;
  const int cb = (bx >> 4) & 3;
  const int b = bx >> 6;
  const int oh0 = ohb * 16, ow0 = owb * 64, c0 = cb * 64;
  const int ih0 = (oh0 >> 1) - 1;                    // may be -1
  const int iw_lo = (ow0 >> 1) - 1;
  const int aligned = (iw_lo < 0 ? 0 : iw_lo) & ~15; // 0 or 16

  for (int i = tid; i < 64 * 10 * 12; i += 256) {    // float4 loads along iw
    int c = i / 120;
    int rem = i - c * 120;
    int r = rem / 12;
    int w4 = (rem - r * 12) * 4;
    int gr = ih0 + r;
    gr = gr < 0 ? 0 : (gr > 63 ? 63 : gr);
    const float4 v = *(const float4*)&x[(((b * 256 + c0 + c) * 64) + gr) * 64 + aligned + w4];
    int base = (r * 48 + w4) * 66 + c;
    lx[base]       = __float2bfloat16(v.x);
    lx[base + 66]  = __float2bfloat16(v.y);
    lx[base + 132] = __float2bfloat16(v.z);
    lx[base + 198] = __float2bfloat16(v.w);
  }
  __syncthreads();

  const int c_l = tid & 63;
  const int owq = tid >> 6;
  for (int it = 0; it < 256; ++it) {
    int oh_l = it >> 4;
    int ow_l = (it & 15) * 4 + owq;
    int oh = oh0 + oh_l, ow = ow0 + ow_l;
    int ihA = (oh >> 1) - ((oh & 1) ^ 1);            // first tap row
    float wh = (oh & 1) ? 0.75f : 0.25f;             // its weight
    int iwA = (ow >> 1) - ((ow & 1) ^ 1);
    float wwt = (ow & 1) ? 0.75f : 0.25f;
    int r0 = ihA - ih0;                               // slot content is pre-clamped
    int w0 = (iwA < 0 ? 0 : iwA) - aligned;
    int w1t = iwA + 1; w1t = w1t > 63 ? 63 : w1t;
    int w1 = w1t - aligned;
    float t00 = __bfloat162float(lx[(r0 * 48 + w0) * 66 + c_l]);
    float t01 = __bfloat162float(lx[(r0 * 48 + w1) * 66 + c_l]);
    float t10 = __bfloat162float(lx[((r0 + 1) * 48 + w0) * 66 + c_l]);
    float t11 = __bfloat162float(lx[((r0 + 1) * 48 + w1) * 66 + c_l]);
    float v = wh * (wwt * t00 + (1.f - wwt) * t01) + (1.f - wh) * (wwt * t10 + (1.f - wwt) * t11);
    up[(((size_t)(b * 128 + oh) * 128) + ow) * 256 + c0 + c_l] = __float2bfloat16(v);
  }
}

// ---------------- Conv: implicit GEMM, M=128 (one out row) x N=128 couts, MFMA bf16 ----------------
// grid: 1024 blocks = b(8) x oh(128), 256 threads (4 waves, 2x2 wave grid of 64x64 tiles)
__global__ __launch_bounds__(256, 2) void conv_kernel(const __hip_bfloat16* __restrict__ up,
                                                      const __hip_bfloat16* __restrict__ Wr,
                                                      float* __restrict__ out,
                                                      float* __restrict__ gstats) {
  __shared__ __align__(16) unsigned short lA[132 * 64];  // [iw+2 halo rows][64 ch], 8x16B chunks/row, XOR swizzled
  __shared__ __align__(16) unsigned short lB[128 * 64];  // [cout][64 ch], swizzled
  __shared__ __align__(16) float ep[16 * 132];           // epilogue transpose [16 couts][128 m + 4 pad]
  __shared__ float lsum[128], lssq[128];

  const int tid = threadIdx.x;
  const int lane = tid & 63;
  const int wave = tid >> 6;
  const int b = blockIdx.x >> 7;
  const int oh = blockIdx.x & 127;
  const int wm = wave >> 1, wn = wave & 1;
  const int lane15 = lane & 15;
  const int quad = lane >> 4;
  const f4v zero4 = {0.f, 0.f, 0.f, 0.f};

  if (tid < 128) { lsum[tid] = 0.f; lssq[tid] = 0.f; }
  if (tid < 32) {  // zero halo rows 0,1,130,131 (conv zero-padding)
    int rsel = tid >> 3;
    int r = (rsel < 2) ? rsel : (128 + rsel);
    int pc = tid & 7;
    *(f4v*)&lA[(r * 8 + pc) * 8] = zero4;
  }

  f4v acc[4][4];
#pragma unroll
  for (int i = 0; i < 4; ++i)
#pragma unroll
    for (int j = 0; j < 4; ++j) acc[i][j] = zero4;

  for (int kh = 0; kh < 5; ++kh) {
    const int ih = oh + kh - 2;
    if (ih < 0 || ih >= 128) continue;  // zero-pad rows: skip (uniform)
    const __hip_bfloat16* uprow = up + (size_t)(b * 128 + ih) * 128 * 256;
    for (int cb = 0; cb < 4; ++cb) {
      const int c0 = cb * 64;
      __syncthreads();  // WAR on lA (and lB)
#pragma unroll
      for (int t = 0; t < 4; ++t) {  // stage lA rows 2..129 (iw 0..127)
        int p = wave * 256 + t * 64 + lane;  // phys chunk 0..1023
        int riw = p >> 3;
        int pc = p & 7;
        int r = riw + 2;
        int cq = pc ^ (r & 7);
        async_copy16(uprow + riw * 256 + c0 + cq * 8,
                     (void*)&lA[(16 + wave * 256 + t * 64) * 8]);
      }
      for (int kw = 0; kw < 5; ++kw) {
        if (kw) __syncthreads();  // WAR on lB
        const __hip_bfloat16* wrow = Wr + (size_t)(kh * 5 + kw) * 128 * 256;
#pragma unroll
        for (int t = 0; t < 4; ++t) {  // stage lB [cout][64ch]
          int p = wave * 256 + t * 64 + lane;
          int n = p >> 3;
          int pc = p & 7;
          int cq = pc ^ (n & 7);
          async_copy16(wrow + n * 256 + c0 + cq * 8,
                       (void*)&lB[(wave * 256 + t * 64) * 8]);
        }
        __syncthreads();  // RAW (drains vmcnt)
#pragma unroll
        for (int ks = 0; ks < 2; ++ks) {
          s8v a[4], bb[4];
          const int cq = ks * 4 + quad;
#pragma unroll
          for (int mt = 0; mt < 4; ++mt) {
            int r = wm * 64 + mt * 16 + lane15 + kw;  // shifted by kw; halo rows are zero
            a[mt] = *(const s8v*)&lA[(r * 8 + (cq ^ (r & 7))) * 8];
          }
#pragma unroll
          for (int nt = 0; nt < 4; ++nt) {
            int n = wn * 64 + nt * 16 + lane15;
            bb[nt] = *(const s8v*)&lB[(n * 8 + (cq ^ (n & 7))) * 8];
          }
#pragma unroll
          for (int mt = 0; mt < 4; ++mt)
#pragma unroll
            for (int nt = 0; nt < 4; ++nt)
              acc[mt][nt] = __builtin_amdgcn_mfma_f32_16x16x32_bf16(a[mt], bb[nt], acc[mt][nt], 0, 0, 0);
        }
      }
    }
  }

  __syncthreads();
#pragma unroll 1
  for (int g = 0; g < 8; ++g) {  // 8 groups of 16 couts
    if ((g >> 2) == wn) {
      const int nt = g & 3;
#pragma unroll
      for (int mt = 0; mt < 4; ++mt) {
        int mcol = wm * 64 + mt * 16 + quad * 4;  // D: n=lane&15, m=quad*4+reg
        *(f4v*)&ep[lane15 * 132 + mcol] = acc[mt][nt];
      }
    }
    __syncthreads();
#pragma unroll
    for (int it = 0; it < 2; ++it) {
      int nl = (tid >> 5) + it * 8;
      int m4 = (tid & 31) * 4;
      f4v v = *(const f4v*)&ep[nl * 132 + m4];
      int cc = g * 16 + nl;
      *(f4v*)&out[((size_t)(b * 128 + cc) * 128 + oh) * 128 + m4] = v;
      float s = v.x + v.y + v.z + v.w;
      float ss = v.x * v.x + v.y * v.y + v.z * v.z + v.w * v.w;
#pragma unroll
      for (int off = 16; off > 0; off >>= 1) {
        s += __shfl_xor(s, off, 32);
        ss += __shfl_xor(ss, off, 32);
      }
      if ((tid & 31) == 0) { lsum[cc] = s; lssq[cc] = ss; }  // each cc written exactly once
    }
    __syncthreads();
  }
  if (tid < 128) {
    atomicAdd(&gstats[tid], lsum[tid]);
    atomicAdd(&gstats[128 + tid], lssq[tid]);
  }
}

// ---------------- BN scale/bias from accumulated stats ----------------
__global__ void scalebias_kernel(const float* __restrict__ gstats, const float* __restrict__ gamma,
                                 const float* __restrict__ beta, float* __restrict__ sb) {
  int c = threadIdx.x;
  float mean = gstats[c] * (1.f / 131072.f);
  float var = gstats[128 + c] * (1.f / 131072.f) - mean * mean;
  float inv = gamma[c] * rsqrtf(var + 1e-5f);
  sb[c] = inv;
  sb[128 + c] = beta[c] - mean * inv;
}

// ---------------- Normalize + ReLU in-place on d_out ----------------
__global__ void norm_kernel(float* __restrict__ out, const float* __restrict__ sb) {
  int i = blockIdx.x * 256 + threadIdx.x;  // float4 index, 4194304 total
  f4v v = ((f4v*)out)[i];
  int c = (i >> 12) & 127;
  float sc = sb[c], bi = sb[128 + c];
  v.x = fmaxf(fmaf(v.x, sc, bi), 0.f);
  v.y = fmaxf(fmaf(v.y, sc, bi), 0.f);
  v.z = fmaxf(fmaf(v.z, sc, bi), 0.f);
  v.w = fmaxf(fmaf(v.w, sc, bi), 0.f);
  ((f4v*)out)[i] = v;
}

extern "C" void kernel_launch(void* const* d_in, const int* in_sizes, int n_in,
                              void* d_out, int out_size, void* d_ws, size_t ws_size,
                              hipStream_t stream) {
  (void)in_sizes; (void)n_in; (void)out_size; (void)ws_size;
  const float* x = (const float*)d_in[0];
  const float* W = (const float*)d_in[1];
  const float* gamma = (const float*)d_in[2];
  const float* beta = (const float*)d_in[3];
  float* out = (float*)d_out;
  char* ws = (char*)d_ws;
  __hip_bfloat16* up = (__hip_bfloat16*)ws;                       // 67,108,864 B
  __hip_bfloat16* Wr = (__hip_bfloat16*)(ws + 67108864);          // 1,638,400 B
  float* gstats = (float*)(ws + 67108864 + 1638400);              // sum[128], sumsq[128]
  float* sb = gstats + 256;                                       // scale[128], bias[128]

  hipMemsetAsync(gstats, 0, 256 * sizeof(float), stream);
  wpack_kernel<<<3200, 256, 0, stream>>>(W, Wr);
  upsample_kernel<<<512, 256, 0, stream>>>(x, up);
  conv_kernel<<<1024, 256, 0, stream>>>(up, Wr, out, gstats);
  scalebias_kernel<<<1, 128, 0, stream>>>(gstats, gamma, beta, sb);
  norm_kernel<<<16384, 256, 0, stream>>>(out, sb);
}